// Round 4
// baseline (480.782 us; speedup 1.0000x reference)
//
#include <hip/hip_runtime.h>

// ---------------------------------------------------------------------------
// RVMixtureSynthesizers: q = query@Wq^T + bq ; k = key@Wk^T + bk
//   energy = q@k^T + attn_bias ; attention = softmax(energy) ; out = attention@value
// Outputs: out [16,1024,1024] fp32, attention [16,1024,1024] fp32 (concat in d_out)
//
// R3: minimal-phase K-loop (T3-min + T4 counted vmcnt): per K-tile ONE
// {stage(t+1); vmcnt(8); barrier; reads+96 MFMA; barrier} region. 2 barriers
// per K-tile (was 6), no sched_barrier in the compute region, no setprio.
// Split-bf16 (hh+hl+lh) for proj and QK^T; PV plain bf16.
// ---------------------------------------------------------------------------

#define AS1 __attribute__((address_space(1)))
#define AS3 __attribute__((address_space(3)))
#define VMCNT(n) asm volatile("s_waitcnt vmcnt(" #n ")" ::: "memory")
#define SBARRIER asm volatile("s_barrier" ::: "memory")

typedef __bf16 bf16;
typedef __bf16 bf16x4 __attribute__((ext_vector_type(4)));
typedef __bf16 bf16x8 __attribute__((ext_vector_type(8)));
typedef float  f32x4  __attribute__((ext_vector_type(4)));

constexpr int BATCH = 16;
constexpr int S = 1024;
constexpr int D = 1024;
constexpr long NBSD = (long)BATCH * S * D;   // 16777216

constexpr int GBM = 256, GBN = 256, GBK = 32;
constexpr int NTK = 1024 / GBK;              // 32 K-tiles
constexpr int ARR = GBM * GBK;               // 8192 elems = 16 KB per array

__device__ __forceinline__ void stage16(const bf16* src, const bf16* dst) {
  __builtin_amdgcn_global_load_lds((const AS1 void*)src, (AS3 void*)dst, 16, 0, 0);
}

// ---------------------------------------------------------------------------
// fp32 -> (hi bf16, lo bf16) split conversion, vectorized x4
__global__ __launch_bounds__(256) void split_convert(
    const float* __restrict__ in, bf16* __restrict__ hi, bf16* __restrict__ lo, int n4) {
  int i = blockIdx.x * blockDim.x + threadIdx.x;
  int stride = gridDim.x * blockDim.x;
  for (; i < n4; i += stride) {
    f32x4 x = ((const f32x4*)in)[i];
    bf16x4 h, l;
#pragma unroll
    for (int j = 0; j < 4; ++j) {
      float v = x[j];
      bf16 hh = (bf16)v;
      h[j] = hh;
      l[j] = (bf16)(v - (float)hh);
    }
    ((bf16x4*)hi)[i] = h;
    ((bf16x4*)lo)[i] = l;
  }
}

// ---------------------------------------------------------------------------
// value [b][t][d] fp32 -> valueT [b][d][t] bf16
__global__ __launch_bounds__(256) void transpose_convert(
    const float* __restrict__ v, bf16* __restrict__ vT) {
  __shared__ float tile[32][33];
  const int b = blockIdx.z;
  const int t0 = blockIdx.y * 32, d0 = blockIdx.x * 32;
  const int tx = threadIdx.x & 31, ty = threadIdx.x >> 5;
  const float* src = v + (long)b * S * D;
#pragma unroll
  for (int i = 0; i < 4; ++i)
    tile[ty + i * 8][tx] = src[(long)(t0 + ty + i * 8) * D + d0 + tx];
  __syncthreads();
  bf16* dst = vT + (long)b * D * S;
#pragma unroll
  for (int i = 0; i < 4; ++i)
    dst[(long)(d0 + ty + i * 8) * S + t0 + tx] = (bf16)tile[tx][ty + i * 8];
}

// ---------------------------------------------------------------------------
// Minimal-phase split-bf16 GEMM. BM=BN=256, BK=32, 512 thr (8 waves 2x4,
// 128x64 per wave). LDS: 2 slots x {Ah,Al,Bh,Bl} x 16KB = 128KB.
// Per K-tile: stage t+1 (8 DMA) ; vmcnt(8) ; barrier ;
//             24 ds_read + 96 MFMA (hh,hl,lh) compiler-scheduled ; barrier.
// EPI=0: proj (col bias, split-bf16 out).  EPI=1: energy (full bias, fp32 out).
template <int EPI>
__global__ __launch_bounds__(512, 2) void gemm8_split(
    const bf16* __restrict__ Ah_g, const bf16* __restrict__ Al_g, long a_bs,
    const bf16* __restrict__ Bh_g, const bf16* __restrict__ Bl_g, long b_bs,
    const float* __restrict__ bias,
    bf16* __restrict__ Ch, bf16* __restrict__ Cl,
    float* __restrict__ Cf, long c_bs) {
  __shared__ bf16 lds[2 * 4 * ARR];   // 128 KB

  const int tid = threadIdx.x;
  const int lane = tid & 63, wid = tid >> 6;
  const int wr = wid >> 2, wc = wid & 3;          // 2x4 wave grid
  const int fr = lane & 15, fq = lane >> 4;
  const int fsw = (fr >> 1) & 3;

  // T1 bijective XCD swizzle (nwg=256)
  const int w = blockIdx.x;
  const int swz = (w & 7) * 32 + (w >> 3);
  int z, by, bx;
  if constexpr (EPI == 0) { z = 0; by = swz >> 2; bx = swz & 3; }
  else { z = swz >> 4; by = (swz >> 2) & 3; bx = swz & 3; }
  const long brow = (long)by * GBM, bcol = (long)bx * GBN;

  const bf16* A_h = Ah_g + (long)z * a_bs;
  const bf16* A_l = Al_g + (long)z * a_bs;
  const bf16* B_h = Bh_g + (long)z * b_bs;
  const bf16* B_l = Bl_g + (long)z * b_bs;

  const int srow = tid >> 2;                                  // 0..127
  const int csw = ((tid & 3) ^ ((srow >> 1) & 3)) * 8;        // source pre-swizzle
  const long asrc = (brow + srow) * 1024 + csw;
  const long bsrc = (bcol + srow) * 1024 + csw;
  const int dstoff = wid * 512;                               // wave-uniform base

  // fragment LDS element offsets (chunk-XOR swizzled, conflict-free PMC-verified)
  const int aoffb = (wr * 128 + fr) * 32 + (fq ^ fsw) * 8;    // + m*512
  const int boffb = (wc * 64 + fr) * 32 + (fq ^ fsw) * 8;     // + n*512

  f32x4 acc[8][4] = {};

#define STG(slot, arr, base, koff, rr) \
  stage16((base) + (koff) + (long)(rr) * 131072, \
          lds + ((slot) * 4 + (arr)) * ARR + (rr) * 4096 + dstoff)

  // prologue: stage tile 0 into slot 0 (awaited by t=0's VMCNT(8))
  STG(0, 0, A_h + asrc, 0, 0); STG(0, 0, A_h + asrc, 0, 1);
  STG(0, 2, B_h + bsrc, 0, 0); STG(0, 2, B_h + bsrc, 0, 1);
  STG(0, 3, B_l + bsrc, 0, 0); STG(0, 3, B_l + bsrc, 0, 1);
  STG(0, 1, A_l + asrc, 0, 0); STG(0, 1, A_l + asrc, 0, 1);

  for (int t = 0; t < NTK; ++t) {
    const int cur = t & 1, nxt = cur ^ 1;
    const bf16* lA_h = lds + (cur * 4 + 0) * ARR;
    const bf16* lA_l = lds + (cur * 4 + 1) * ARR;
    const bf16* lB_h = lds + (cur * 4 + 2) * ARR;
    const bf16* lB_l = lds + (cur * 4 + 3) * ARR;

    // (a) stage tile t+1 ; (b) counted wait: tile t's 8 DMAs done
    if (t + 1 < NTK) {
      const long kn = (long)(t + 1) * GBK;
      STG(nxt, 0, A_h + asrc, kn, 0); STG(nxt, 0, A_h + asrc, kn, 1);
      STG(nxt, 2, B_h + bsrc, kn, 0); STG(nxt, 2, B_h + bsrc, kn, 1);
      STG(nxt, 3, B_l + bsrc, kn, 0); STG(nxt, 3, B_l + bsrc, kn, 1);
      STG(nxt, 1, A_l + asrc, kn, 0); STG(nxt, 1, A_l + asrc, kn, 1);
      VMCNT(8);
    } else {
      VMCNT(0);
    }
    __builtin_amdgcn_sched_barrier(0);   // pin issue order at the wait point only
    SBARRIER;                            // publish cur slot across waves

    // (d,f) one compiler-scheduled region: reads + 96 MFMA
    bf16x8 ah[8], bh[4];
#pragma unroll
    for (int m = 0; m < 8; ++m) ah[m] = *(const bf16x8*)&lA_h[aoffb + m * 512];
#pragma unroll
    for (int n = 0; n < 4; ++n) bh[n] = *(const bf16x8*)&lB_h[boffb + n * 512];
#pragma unroll
    for (int n = 0; n < 4; ++n)
#pragma unroll
      for (int m = 0; m < 8; ++m)
        acc[m][n] = __builtin_amdgcn_mfma_f32_16x16x32_bf16(ah[m], bh[n], acc[m][n], 0, 0, 0);

    bf16x8 bl[4];
#pragma unroll
    for (int n = 0; n < 4; ++n) bl[n] = *(const bf16x8*)&lB_l[boffb + n * 512];
#pragma unroll
    for (int n = 0; n < 4; ++n)
#pragma unroll
      for (int m = 0; m < 8; ++m)
        acc[m][n] = __builtin_amdgcn_mfma_f32_16x16x32_bf16(ah[m], bl[n], acc[m][n], 0, 0, 0);

    bf16x8 al[8];
#pragma unroll
    for (int m = 0; m < 8; ++m) al[m] = *(const bf16x8*)&lA_l[aoffb + m * 512];
#pragma unroll
    for (int n = 0; n < 4; ++n)
#pragma unroll
      for (int m = 0; m < 8; ++m)
        acc[m][n] = __builtin_amdgcn_mfma_f32_16x16x32_bf16(al[m], bh[n], acc[m][n], 0, 0, 0);

    SBARRIER;                            // all reads of cur done before t+1 stages it
  }
#undef STG

  // Epilogue. C/D frag: col = lane&15, row = (lane>>4)*4 + j
  if constexpr (EPI == 0) {
#pragma unroll
    for (int n = 0; n < 4; ++n) {
      const long col = bcol + wc * 64 + n * 16 + fr;
      const float bv = bias[col];
#pragma unroll
      for (int m = 0; m < 8; ++m) {
        const long row0 = brow + wr * 128 + m * 16 + fq * 4;
#pragma unroll
        for (int j = 0; j < 4; ++j) {
          const float c = acc[m][n][j] + bv;
          const bf16 h = (bf16)c;
          const bf16 l = (bf16)(c - (float)h);
          const long idx = (row0 + j) * 1024 + col;
          Ch[idx] = h;
          Cl[idx] = l;
        }
      }
    }
  } else {
    float* Cz = Cf + (long)z * c_bs;
#pragma unroll
    for (int n = 0; n < 4; ++n) {
      const long col = bcol + wc * 64 + n * 16 + fr;
#pragma unroll
      for (int m = 0; m < 8; ++m) {
        const long row0 = brow + wr * 128 + m * 16 + fq * 4;
#pragma unroll
        for (int j = 0; j < 4; ++j) {
          const long row = row0 + j;
          Cz[row * 1024 + col] = acc[m][n][j] + bias[row * 1024 + col];
        }
      }
    }
  }
}

// ---------------------------------------------------------------------------
// Minimal-phase plain bf16 GEMM (PV). 2 slots x {A,B} x 16KB = 64KB.
// Per K-tile: stage t+1 (4 DMA) ; vmcnt(4) ; barrier ; 12 reads + 32 MFMA ; barrier.
__global__ __launch_bounds__(512, 2) void gemm8_plain(
    const bf16* __restrict__ A_g, long a_bs,
    const bf16* __restrict__ B_g, long b_bs,
    float* __restrict__ C, long c_bs) {
  __shared__ bf16 lds[2 * 2 * ARR];   // 64 KB

  const int tid = threadIdx.x;
  const int lane = tid & 63, wid = tid >> 6;
  const int wr = wid >> 2, wc = wid & 3;
  const int fr = lane & 15, fq = lane >> 4;
  const int fsw = (fr >> 1) & 3;

  const int w = blockIdx.x;
  const int swz = (w & 7) * 32 + (w >> 3);
  const int z = swz >> 4, by = (swz >> 2) & 3, bx = swz & 3;
  const long brow = (long)by * GBM, bcol = (long)bx * GBN;

  const bf16* A = A_g + (long)z * a_bs;
  const bf16* B = B_g + (long)z * b_bs;

  const int srow = tid >> 2;
  const int csw = ((tid & 3) ^ ((srow >> 1) & 3)) * 8;
  const long asrc = (brow + srow) * 1024 + csw;
  const long bsrc = (bcol + srow) * 1024 + csw;
  const int dstoff = wid * 512;

  const int aoffb = (wr * 128 + fr) * 32 + (fq ^ fsw) * 8;
  const int boffb = (wc * 64 + fr) * 32 + (fq ^ fsw) * 8;

  f32x4 acc[8][4] = {};

#define STG2(slot, arr, base, koff, rr) \
  stage16((base) + (koff) + (long)(rr) * 131072, \
          lds + ((slot) * 2 + (arr)) * ARR + (rr) * 4096 + dstoff)

  // prologue: stage tile 0 into slot 0
  STG2(0, 0, A + asrc, 0, 0); STG2(0, 0, A + asrc, 0, 1);
  STG2(0, 1, B + bsrc, 0, 0); STG2(0, 1, B + bsrc, 0, 1);

  for (int t = 0; t < NTK; ++t) {
    const int cur = t & 1, nxt = cur ^ 1;
    const bf16* lA = lds + (cur * 2 + 0) * ARR;
    const bf16* lB = lds + (cur * 2 + 1) * ARR;

    if (t + 1 < NTK) {
      const long kn = (long)(t + 1) * GBK;
      STG2(nxt, 0, A + asrc, kn, 0); STG2(nxt, 0, A + asrc, kn, 1);
      STG2(nxt, 1, B + bsrc, kn, 0); STG2(nxt, 1, B + bsrc, kn, 1);
      VMCNT(4);
    } else {
      VMCNT(0);
    }
    __builtin_amdgcn_sched_barrier(0);
    SBARRIER;

    bf16x8 ah[8], bh[4];
#pragma unroll
    for (int m = 0; m < 8; ++m) ah[m] = *(const bf16x8*)&lA[aoffb + m * 512];
#pragma unroll
    for (int n = 0; n < 4; ++n) bh[n] = *(const bf16x8*)&lB[boffb + n * 512];
#pragma unroll
    for (int n = 0; n < 4; ++n)
#pragma unroll
      for (int m = 0; m < 8; ++m)
        acc[m][n] = __builtin_amdgcn_mfma_f32_16x16x32_bf16(ah[m], bh[n], acc[m][n], 0, 0, 0);

    SBARRIER;
  }
#undef STG2

  float* Cz = C + (long)z * c_bs;
#pragma unroll
  for (int n = 0; n < 4; ++n) {
    const long col = bcol + wc * 64 + n * 16 + fr;
#pragma unroll
    for (int m = 0; m < 8; ++m) {
      const long row0 = brow + wr * 128 + m * 16 + fq * 4;
#pragma unroll
      for (int j = 0; j < 4; ++j)
        Cz[(row0 + j) * 1024 + col] = acc[m][n][j];
    }
  }
}

// ---------------------------------------------------------------------------
// Row softmax (fp32 in place) + bf16 copy for PV.
__global__ __launch_bounds__(256) void softmax_rows(
    float* __restrict__ attn, bf16* __restrict__ attn_bf) {
  const long row = blockIdx.x;
  float* p = attn + row * 1024;
  const int tid = threadIdx.x, lane = tid & 63, wid = tid >> 6;

  f32x4 x = ((const f32x4*)p)[tid];
  float m = fmaxf(fmaxf(x[0], x[1]), fmaxf(x[2], x[3]));
#pragma unroll
  for (int off = 32; off; off >>= 1) m = fmaxf(m, __shfl_xor(m, off));
  __shared__ float redm[4];
  if (lane == 0) redm[wid] = m;
  __syncthreads();
  m = fmaxf(fmaxf(redm[0], redm[1]), fmaxf(redm[2], redm[3]));

  f32x4 e;
#pragma unroll
  for (int j = 0; j < 4; ++j) e[j] = __expf(x[j] - m);
  float s = e[0] + e[1] + e[2] + e[3];
#pragma unroll
  for (int off = 32; off; off >>= 1) s += __shfl_xor(s, off);
  __shared__ float reds[4];
  if (lane == 0) reds[wid] = s;
  __syncthreads();
  s = reds[0] + reds[1] + reds[2] + reds[3];

  const float inv = 1.0f / s;
  f32x4 r;
  bf16x4 rb;
#pragma unroll
  for (int j = 0; j < 4; ++j) {
    r[j] = e[j] * inv;
    rb[j] = (bf16)r[j];
  }
  ((f32x4*)p)[tid] = r;
  ((bf16x4*)(attn_bf + row * 1024))[tid] = rb;
}

// ---------------------------------------------------------------------------
extern "C" void kernel_launch(void* const* d_in, const int* in_sizes, int n_in,
                              void* d_out, int out_size, void* d_ws, size_t ws_size,
                              hipStream_t stream) {
  const float* query     = (const float*)d_in[0];
  const float* key       = (const float*)d_in[1];
  const float* value     = (const float*)d_in[2];
  const float* attn_bias = (const float*)d_in[3];
  const float* Wq        = (const float*)d_in[4];
  const float* bq        = (const float*)d_in[5];
  const float* Wk        = (const float*)d_in[6];
  const float* bk        = (const float*)d_in[7];

  float* out  = (float*)d_out;          // [16,1024,1024]
  float* attn = out + NBSD;             // [16,1024,1024]

  // ws carve (bf16 elements). Total = 6*NBSD + 4*D*D = 200 MiB.
  bf16* ws    = (bf16*)d_ws;
  bf16* q_hi  = ws;
  bf16* q_lo  = ws + NBSD;
  bf16* k_hi  = ws + 2 * NBSD;
  bf16* k_lo  = ws + 3 * NBSD;
  bf16* Wq_hi = ws + 4 * NBSD;
  bf16* Wq_lo = Wq_hi + (long)D * D;
  bf16* Wk_hi = Wq_lo + (long)D * D;
  bf16* Wk_lo = Wk_hi + (long)D * D;
  bf16* scr   = Wk_lo + (long)D * D;    // 2*NBSD scratch
  bf16* key_hi = scr;
  bf16* key_lo = scr + NBSD;
  bf16* valueT  = scr;                  // reused after key splits die
  bf16* attn_bf = scr + NBSD;
  bf16* query_hi = (bf16*)d_out;        // lives in `out` region until PV
  bf16* query_lo = query_hi + NBSD;

  // 1) split conversions
  split_convert<<<2048, 256, 0, stream>>>(query, query_hi, query_lo, (int)(NBSD / 4));
  split_convert<<<2048, 256, 0, stream>>>(key, key_hi, key_lo, (int)(NBSD / 4));
  split_convert<<<512, 256, 0, stream>>>(Wq, Wq_hi, Wq_lo, D * D / 4);
  split_convert<<<512, 256, 0, stream>>>(Wk, Wk_hi, Wk_lo, D * D / 4);

  // 2) projections: [16384,1024] x [1024,1024]^T (grid 64x4 = 256 blocks)
  gemm8_split<0><<<256, 512, 0, stream>>>(query_hi, query_lo, 0, Wq_hi, Wq_lo, 0,
                                          bq, q_hi, q_lo, nullptr, 0);
  gemm8_split<0><<<256, 512, 0, stream>>>(key_hi, key_lo, 0, Wk_hi, Wk_lo, 0,
                                          bk, k_hi, k_lo, nullptr, 0);

  // 3) value transpose (key splits now dead)
  transpose_convert<<<dim3(32, 32, 16), 256, 0, stream>>>(value, valueT);

  // 4) energy = q k^T + bias (grid 16 z x 4x4 = 256 blocks)
  gemm8_split<1><<<256, 512, 0, stream>>>(q_hi, q_lo, (long)S * D, k_hi, k_lo, (long)S * D,
                                          attn_bias, nullptr, nullptr, attn, (long)S * S);

  // 5) softmax in place + bf16 copy
  softmax_rows<<<BATCH * S, 256, 0, stream>>>(attn, attn_bf);

  // 6) out = attention @ value
  gemm8_plain<<<256, 512, 0, stream>>>(attn_bf, (long)S * S, valueT, (long)D * S,
                                       out, (long)S * D);
}

// Round 5
// 460.601 us; speedup vs baseline: 1.0438x; 1.0438x over previous
//
#include <hip/hip_runtime.h>

// ---------------------------------------------------------------------------
// RVMixtureSynthesizers: q = query@Wq^T + bq ; k = key@Wk^T + bk
//   energy = q@k^T + attn_bias ; attention = softmax(energy) ; out = attention@value
// Outputs: out [16,1024,1024] fp32, attention [16,1024,1024] fp32 (concat in d_out)
//
// R4: split GEMM -> 6-phase pipelined schedule (m201-style): per phase issue
// NEXT cluster's ds_reads + 2 stage-DMAs, barrier, counted lgkmcnt (retires
// only old reads), setprio'd 16-MFMA cluster. Counted vmcnt 2x/tile.
// Split-bf16 (hh+hl+lh) for proj and QK^T; PV plain bf16 (unchanged R3).
// ---------------------------------------------------------------------------

#define AS1 __attribute__((address_space(1)))
#define AS3 __attribute__((address_space(3)))
#define VMCNT(n) asm volatile("s_waitcnt vmcnt(" #n ")" ::: "memory")
#define LGKM(n)  asm volatile("s_waitcnt lgkmcnt(" #n ")" ::: "memory")
#define SBARRIER asm volatile("s_barrier" ::: "memory")
#define SB0 __builtin_amdgcn_sched_barrier(0)

typedef __bf16 bf16;
typedef __bf16 bf16x4 __attribute__((ext_vector_type(4)));
typedef __bf16 bf16x8 __attribute__((ext_vector_type(8)));
typedef float  f32x4  __attribute__((ext_vector_type(4)));

constexpr int BATCH = 16;
constexpr int S = 1024;
constexpr int D = 1024;
constexpr long NBSD = (long)BATCH * S * D;   // 16777216

constexpr int GBM = 256, GBN = 256, GBK = 32;
constexpr int NTK = 1024 / GBK;              // 32 K-tiles
constexpr int ARR = GBM * GBK;               // 8192 elems = 16 KB per array

__device__ __forceinline__ void stage16(const bf16* src, const bf16* dst) {
  __builtin_amdgcn_global_load_lds((const AS1 void*)src, (AS3 void*)dst, 16, 0, 0);
}

// ---------------------------------------------------------------------------
__global__ __launch_bounds__(256) void split_convert(
    const float* __restrict__ in, bf16* __restrict__ hi, bf16* __restrict__ lo, int n4) {
  int i = blockIdx.x * blockDim.x + threadIdx.x;
  int stride = gridDim.x * blockDim.x;
  for (; i < n4; i += stride) {
    f32x4 x = ((const f32x4*)in)[i];
    bf16x4 h, l;
#pragma unroll
    for (int j = 0; j < 4; ++j) {
      float v = x[j];
      bf16 hh = (bf16)v;
      h[j] = hh;
      l[j] = (bf16)(v - (float)hh);
    }
    ((bf16x4*)hi)[i] = h;
    ((bf16x4*)lo)[i] = l;
  }
}

// ---------------------------------------------------------------------------
__global__ __launch_bounds__(256) void transpose_convert(
    const float* __restrict__ v, bf16* __restrict__ vT) {
  __shared__ float tile[32][33];
  const int b = blockIdx.z;
  const int t0 = blockIdx.y * 32, d0 = blockIdx.x * 32;
  const int tx = threadIdx.x & 31, ty = threadIdx.x >> 5;
  const float* src = v + (long)b * S * D;
#pragma unroll
  for (int i = 0; i < 4; ++i)
    tile[ty + i * 8][tx] = src[(long)(t0 + ty + i * 8) * D + d0 + tx];
  __syncthreads();
  bf16* dst = vT + (long)b * D * S;
#pragma unroll
  for (int i = 0; i < 4; ++i)
    dst[(long)(d0 + ty + i * 8) * S + t0 + tx] = (bf16)tile[tx][ty + i * 8];
}

// ---------------------------------------------------------------------------
// 6-phase pipelined split-bf16 GEMM. BM=BN=256, BK=32, 512 thr (8 waves 2x4,
// 128x64 per wave). LDS: 2 bufs x {Ah,Al,Bh,Bl} x 16KB = 128KB.
// Clusters: C1 hh(n01) C2 hh(n23) C3 hl(n01) C4 hl(n23) C5 lh(n01) C6 lh(n23)
// Each phase issues the reads for a LATER cluster; counted lgkm waits retire
// only the older reads. Stage DMAs: 2/phase P1-P4; vmcnt(2)@P1, vmcnt(4)@P5.
template <int EPI>
__global__ __launch_bounds__(512, 2) void gemm8_split(
    const bf16* __restrict__ Ah_g, const bf16* __restrict__ Al_g, long a_bs,
    const bf16* __restrict__ Bh_g, const bf16* __restrict__ Bl_g, long b_bs,
    const float* __restrict__ bias,
    bf16* __restrict__ Ch, bf16* __restrict__ Cl,
    float* __restrict__ Cf, long c_bs) {
  __shared__ bf16 lds[2 * 4 * ARR];   // 128 KB

  const int tid = threadIdx.x;
  const int lane = tid & 63, wid = tid >> 6;
  const int wr = wid >> 2, wc = wid & 3;          // 2x4 wave grid
  const int fr = lane & 15, fq = lane >> 4;
  const int fsw = (fr >> 1) & 3;

  // T1 bijective XCD swizzle (nwg=256)
  const int w = blockIdx.x;
  const int swz = (w & 7) * 32 + (w >> 3);
  int z, by, bx;
  if constexpr (EPI == 0) { z = 0; by = swz >> 2; bx = swz & 3; }
  else { z = swz >> 4; by = (swz >> 2) & 3; bx = swz & 3; }
  const long brow = (long)by * GBM, bcol = (long)bx * GBN;

  const bf16* A_h = Ah_g + (long)z * a_bs;
  const bf16* A_l = Al_g + (long)z * a_bs;
  const bf16* B_h = Bh_g + (long)z * b_bs;
  const bf16* B_l = Bl_g + (long)z * b_bs;

  const int srow = tid >> 2;                                  // 0..127
  const int csw = ((tid & 3) ^ ((srow >> 1) & 3)) * 8;        // source pre-swizzle
  const long asrc = (brow + srow) * 1024 + csw;
  const long bsrc = (bcol + srow) * 1024 + csw;
  const int dstoff = wid * 512;                               // wave-uniform base

  const int aoffb = (wr * 128 + fr) * 32 + (fq ^ fsw) * 8;    // + m*512
  const int boffb = (wc * 64 + fr) * 32 + (fq ^ fsw) * 8;     // + n*512

  f32x4 acc[8][4] = {};
  bf16x8 ah[8], al[8], bh[4], bl[4];

#define STG(slot, arr, base, koff, rr) \
  stage16((base) + (koff) + (long)(rr) * 131072, \
          lds + ((slot) * 4 + (arr)) * ARR + (rr) * 4096 + dstoff)

#define CLUSTER(AF, BF, N0) \
  __builtin_amdgcn_s_setprio(1); \
  _Pragma("unroll") \
  for (int m = 0; m < 8; ++m) \
    acc[m][N0] = __builtin_amdgcn_mfma_f32_16x16x32_bf16(AF[m], BF[N0], acc[m][N0], 0, 0, 0); \
  _Pragma("unroll") \
  for (int m = 0; m < 8; ++m) \
    acc[m][N0+1] = __builtin_amdgcn_mfma_f32_16x16x32_bf16(AF[m], BF[N0+1], acc[m][N0+1], 0, 0, 0); \
  __builtin_amdgcn_s_setprio(0)

  // ---- prologue: stage tile 0 (order Ah,Bh,Bl,Al), publish Ah+Bh, preload C1 operands
  STG(0, 0, A_h + asrc, 0, 0); STG(0, 0, A_h + asrc, 0, 1);
  STG(0, 2, B_h + bsrc, 0, 0); STG(0, 2, B_h + bsrc, 0, 1);
  STG(0, 3, B_l + bsrc, 0, 0); STG(0, 3, B_l + bsrc, 0, 1);
  STG(0, 1, A_l + asrc, 0, 0); STG(0, 1, A_l + asrc, 0, 1);
  VMCNT(4);
  SBARRIER;
  {
    const bf16* lA_h0 = lds;
    const bf16* lB_h0 = lds + 2 * ARR;
#pragma unroll
    for (int m = 0; m < 8; ++m) ah[m] = *(const bf16x8*)&lA_h0[aoffb + m * 512];
    bh[0] = *(const bf16x8*)&lB_h0[boffb];
    bh[1] = *(const bf16x8*)&lB_h0[boffb + 512];
  }

  for (int t = 0; t < NTK; ++t) {
    const int cur = t & 1, nxt = cur ^ 1;
    const long kn = (long)(t + 1) * GBK;
    const bool pf = (t + 1 < NTK);
    const bf16* lA_l = lds + (cur * 4 + 1) * ARR;
    const bf16* lB_h = lds + (cur * 4 + 2) * ARR;
    const bf16* lB_l = lds + (cur * 4 + 3) * ARR;
    const bf16* nA_h = lds + (nxt * 4 + 0) * ARR;
    const bf16* nB_h = lds + (nxt * 4 + 2) * ARR;

    // -------- P1: reads bh23 | stage Ah' | vmcnt(2) | bar | lgkm(2) | C1 hh(n01)
    bh[2] = *(const bf16x8*)&lB_h[boffb + 2 * 512];
    bh[3] = *(const bf16x8*)&lB_h[boffb + 3 * 512];
    if (pf) {
      STG(nxt, 0, A_h + asrc, kn, 0); STG(nxt, 0, A_h + asrc, kn, 1);
      VMCNT(2);
    } else {
      VMCNT(0);
    }
    SBARRIER; LGKM(2); SB0;
    CLUSTER(ah, bh, 0);

    // -------- P2: reads bl01 | stage Bh' | bar | lgkm(2) | C2 hh(n23)
    bl[0] = *(const bf16x8*)&lB_l[boffb];
    bl[1] = *(const bf16x8*)&lB_l[boffb + 512];
    if (pf) { STG(nxt, 2, B_h + bsrc, kn, 0); STG(nxt, 2, B_h + bsrc, kn, 1); }
    SBARRIER; LGKM(2); SB0;
    CLUSTER(ah, bh, 2);

    // -------- P3: reads bl23 | stage Bl' | bar | lgkm(2) | C3 hl(n01)
    bl[2] = *(const bf16x8*)&lB_l[boffb + 2 * 512];
    bl[3] = *(const bf16x8*)&lB_l[boffb + 3 * 512];
    if (pf) { STG(nxt, 3, B_l + bsrc, kn, 0); STG(nxt, 3, B_l + bsrc, kn, 1); }
    SBARRIER; LGKM(2); SB0;
    CLUSTER(ah, bl, 0);

    // -------- P4: reads al0-7 | stage Al' | bar | lgkm(8) | C4 hl(n23)
#pragma unroll
    for (int m = 0; m < 8; ++m) al[m] = *(const bf16x8*)&lA_l[aoffb + m * 512];
    if (pf) { STG(nxt, 1, A_l + asrc, kn, 0); STG(nxt, 1, A_l + asrc, kn, 1); }
    SBARRIER; LGKM(8); SB0;
    CLUSTER(ah, bl, 2);

    // -------- P5: vmcnt(4) [publish Ah',Bh'] | bar | lgkm(0) | C5 lh(n01)
    if (pf) { VMCNT(4); } else { VMCNT(0); }
    SBARRIER; LGKM(0); SB0;
    CLUSTER(al, bh, 0);

    // -------- P6: reads ah',bh'01 from nxt | bar | C6 lh(n23)
    if (pf) {
#pragma unroll
      for (int m = 0; m < 8; ++m) ah[m] = *(const bf16x8*)&nA_h[aoffb + m * 512];
      bh[0] = *(const bf16x8*)&nB_h[boffb];
      bh[1] = *(const bf16x8*)&nB_h[boffb + 512];
    }
    SBARRIER; SB0;
    CLUSTER(al, bh, 2);
  }
#undef STG
#undef CLUSTER

  // Epilogue. C/D frag: col = lane&15, row = (lane>>4)*4 + j
  if constexpr (EPI == 0) {
#pragma unroll
    for (int n = 0; n < 4; ++n) {
      const long col = bcol + wc * 64 + n * 16 + fr;
      const float bv = bias[col];
#pragma unroll
      for (int m = 0; m < 8; ++m) {
        const long row0 = brow + wr * 128 + m * 16 + fq * 4;
#pragma unroll
        for (int j = 0; j < 4; ++j) {
          const float c = acc[m][n][j] + bv;
          const bf16 h = (bf16)c;
          const bf16 l = (bf16)(c - (float)h);
          const long idx = (row0 + j) * 1024 + col;
          Ch[idx] = h;
          Cl[idx] = l;
        }
      }
    }
  } else {
    float* Cz = Cf + (long)z * c_bs;
#pragma unroll
    for (int n = 0; n < 4; ++n) {
      const long col = bcol + wc * 64 + n * 16 + fr;
#pragma unroll
      for (int m = 0; m < 8; ++m) {
        const long row0 = brow + wr * 128 + m * 16 + fq * 4;
#pragma unroll
        for (int j = 0; j < 4; ++j) {
          const long row = row0 + j;
          Cz[row * 1024 + col] = acc[m][n][j] + bias[row * 1024 + col];
        }
      }
    }
  }
}

// ---------------------------------------------------------------------------
// Plain bf16 GEMM (PV), R3 structure: 2 bufs x {A,B} = 64KB; per K-tile
// stage t+1 ; vmcnt(4) ; barrier ; 12 reads + 32 MFMA ; barrier.
__global__ __launch_bounds__(512, 2) void gemm8_plain(
    const bf16* __restrict__ A_g, long a_bs,
    const bf16* __restrict__ B_g, long b_bs,
    float* __restrict__ C, long c_bs) {
  __shared__ bf16 lds[2 * 2 * ARR];   // 64 KB

  const int tid = threadIdx.x;
  const int lane = tid & 63, wid = tid >> 6;
  const int wr = wid >> 2, wc = wid & 3;
  const int fr = lane & 15, fq = lane >> 4;
  const int fsw = (fr >> 1) & 3;

  const int w = blockIdx.x;
  const int swz = (w & 7) * 32 + (w >> 3);
  const int z = swz >> 4, by = (swz >> 2) & 3, bx = swz & 3;
  const long brow = (long)by * GBM, bcol = (long)bx * GBN;

  const bf16* A = A_g + (long)z * a_bs;
  const bf16* B = B_g + (long)z * b_bs;

  const int srow = tid >> 2;
  const int csw = ((tid & 3) ^ ((srow >> 1) & 3)) * 8;
  const long asrc = (brow + srow) * 1024 + csw;
  const long bsrc = (bcol + srow) * 1024 + csw;
  const int dstoff = wid * 512;

  const int aoffb = (wr * 128 + fr) * 32 + (fq ^ fsw) * 8;
  const int boffb = (wc * 64 + fr) * 32 + (fq ^ fsw) * 8;

  f32x4 acc[8][4] = {};

#define STG2(slot, arr, base, koff, rr) \
  stage16((base) + (koff) + (long)(rr) * 131072, \
          lds + ((slot) * 2 + (arr)) * ARR + (rr) * 4096 + dstoff)

  STG2(0, 0, A + asrc, 0, 0); STG2(0, 0, A + asrc, 0, 1);
  STG2(0, 1, B + bsrc, 0, 0); STG2(0, 1, B + bsrc, 0, 1);

  for (int t = 0; t < NTK; ++t) {
    const int cur = t & 1, nxt = cur ^ 1;
    const bf16* lA = lds + (cur * 2 + 0) * ARR;
    const bf16* lB = lds + (cur * 2 + 1) * ARR;

    if (t + 1 < NTK) {
      const long kn = (long)(t + 1) * GBK;
      STG2(nxt, 0, A + asrc, kn, 0); STG2(nxt, 0, A + asrc, kn, 1);
      STG2(nxt, 1, B + bsrc, kn, 0); STG2(nxt, 1, B + bsrc, kn, 1);
      VMCNT(4);
    } else {
      VMCNT(0);
    }
    SB0;
    SBARRIER;

    bf16x8 ah[8], bh[4];
#pragma unroll
    for (int m = 0; m < 8; ++m) ah[m] = *(const bf16x8*)&lA[aoffb + m * 512];
#pragma unroll
    for (int n = 0; n < 4; ++n) bh[n] = *(const bf16x8*)&lB[boffb + n * 512];
#pragma unroll
    for (int n = 0; n < 4; ++n)
#pragma unroll
      for (int m = 0; m < 8; ++m)
        acc[m][n] = __builtin_amdgcn_mfma_f32_16x16x32_bf16(ah[m], bh[n], acc[m][n], 0, 0, 0);

    SBARRIER;
  }
#undef STG2

  float* Cz = C + (long)z * c_bs;
#pragma unroll
  for (int n = 0; n < 4; ++n) {
    const long col = bcol + wc * 64 + n * 16 + fr;
#pragma unroll
    for (int m = 0; m < 8; ++m) {
      const long row0 = brow + wr * 128 + m * 16 + fq * 4;
#pragma unroll
      for (int j = 0; j < 4; ++j)
        Cz[(row0 + j) * 1024 + col] = acc[m][n][j];
    }
  }
}

// ---------------------------------------------------------------------------
__global__ __launch_bounds__(256) void softmax_rows(
    float* __restrict__ attn, bf16* __restrict__ attn_bf) {
  const long row = blockIdx.x;
  float* p = attn + row * 1024;
  const int tid = threadIdx.x, lane = tid & 63, wid = tid >> 6;

  f32x4 x = ((const f32x4*)p)[tid];
  float m = fmaxf(fmaxf(x[0], x[1]), fmaxf(x[2], x[3]));
#pragma unroll
  for (int off = 32; off; off >>= 1) m = fmaxf(m, __shfl_xor(m, off));
  __shared__ float redm[4];
  if (lane == 0) redm[wid] = m;
  __syncthreads();
  m = fmaxf(fmaxf(redm[0], redm[1]), fmaxf(redm[2], redm[3]));

  f32x4 e;
#pragma unroll
  for (int j = 0; j < 4; ++j) e[j] = __expf(x[j] - m);
  float s = e[0] + e[1] + e[2] + e[3];
#pragma unroll
  for (int off = 32; off; off >>= 1) s += __shfl_xor(s, off);
  __shared__ float reds[4];
  if (lane == 0) reds[wid] = s;
  __syncthreads();
  s = reds[0] + reds[1] + reds[2] + reds[3];

  const float inv = 1.0f / s;
  f32x4 r;
  bf16x4 rb;
#pragma unroll
  for (int j = 0; j < 4; ++j) {
    r[j] = e[j] * inv;
    rb[j] = (bf16)r[j];
  }
  ((f32x4*)p)[tid] = r;
  ((bf16x4*)(attn_bf + row * 1024))[tid] = rb;
}

// ---------------------------------------------------------------------------
extern "C" void kernel_launch(void* const* d_in, const int* in_sizes, int n_in,
                              void* d_out, int out_size, void* d_ws, size_t ws_size,
                              hipStream_t stream) {
  const float* query     = (const float*)d_in[0];
  const float* key       = (const float*)d_in[1];
  const float* value     = (const float*)d_in[2];
  const float* attn_bias = (const float*)d_in[3];
  const float* Wq        = (const float*)d_in[4];
  const float* bq        = (const float*)d_in[5];
  const float* Wk        = (const float*)d_in[6];
  const float* bk        = (const float*)d_in[7];

  float* out  = (float*)d_out;          // [16,1024,1024]
  float* attn = out + NBSD;             // [16,1024,1024]

  // ws carve (bf16 elements). Total = 6*NBSD + 4*D*D = 200 MiB.
  bf16* ws    = (bf16*)d_ws;
  bf16* q_hi  = ws;
  bf16* q_lo  = ws + NBSD;
  bf16* k_hi  = ws + 2 * NBSD;
  bf16* k_lo  = ws + 3 * NBSD;
  bf16* Wq_hi = ws + 4 * NBSD;
  bf16* Wq_lo = Wq_hi + (long)D * D;
  bf16* Wk_hi = Wq_lo + (long)D * D;
  bf16* Wk_lo = Wk_hi + (long)D * D;
  bf16* scr   = Wk_lo + (long)D * D;    // 2*NBSD scratch
  bf16* key_hi = scr;
  bf16* key_lo = scr + NBSD;
  bf16* valueT  = scr;                  // reused after key splits die
  bf16* attn_bf = scr + NBSD;
  bf16* query_hi = (bf16*)d_out;        // lives in `out` region until PV
  bf16* query_lo = query_hi + NBSD;

  // 1) split conversions
  split_convert<<<2048, 256, 0, stream>>>(query, query_hi, query_lo, (int)(NBSD / 4));
  split_convert<<<2048, 256, 0, stream>>>(key, key_hi, key_lo, (int)(NBSD / 4));
  split_convert<<<512, 256, 0, stream>>>(Wq, Wq_hi, Wq_lo, D * D / 4);
  split_convert<<<512, 256, 0, stream>>>(Wk, Wk_hi, Wk_lo, D * D / 4);

  // 2) projections: [16384,1024] x [1024,1024]^T (grid 64x4 = 256 blocks)
  gemm8_split<0><<<256, 512, 0, stream>>>(query_hi, query_lo, 0, Wq_hi, Wq_lo, 0,
                                          bq, q_hi, q_lo, nullptr, 0);
  gemm8_split<0><<<256, 512, 0, stream>>>(key_hi, key_lo, 0, Wk_hi, Wk_lo, 0,
                                          bk, k_hi, k_lo, nullptr, 0);

  // 3) value transpose (key splits now dead)
  transpose_convert<<<dim3(32, 32, 16), 256, 0, stream>>>(value, valueT);

  // 4) energy = q k^T + bias (grid 16 z x 4x4 = 256 blocks)
  gemm8_split<1><<<256, 512, 0, stream>>>(q_hi, q_lo, (long)S * D, k_hi, k_lo, (long)S * D,
                                          attn_bias, nullptr, nullptr, attn, (long)S * S);

  // 5) softmax in place + bf16 copy
  softmax_rows<<<BATCH * S, 256, 0, stream>>>(attn, attn_bf);

  // 6) out = attention @ value
  gemm8_plain<<<256, 512, 0, stream>>>(attn_bf, (long)S * S, valueT, (long)D * S,
                                       out, (long)S * D);
}

// Round 6
// 435.909 us; speedup vs baseline: 1.1029x; 1.0566x over previous
//
#include <hip/hip_runtime.h>

// ---------------------------------------------------------------------------
// RVMixtureSynthesizers: q = query@Wq^T + bq ; k = key@Wk^T + bk
//   energy = q@k^T + attn_bias ; attention = softmax(energy) ; out = attention@value
// Outputs: out [16,1024,1024] fp32, attention [16,1024,1024] fp32 (concat in d_out)
//
// R5: split GEMMs ported to mfma_f32_32x32x16_bf16 (2495 TF ceiling, half the
// MFMA instruction count) with 3 phases/K-tile (hh, hl, lh), m201-style:
// {reads; stage; counted vmcnt; barrier; lgkm(0); setprio; 16 MFMA; barrier}.
// Split-bf16 (hh+hl+lh) for proj and QK^T; PV plain bf16 (R3 structure).
// ---------------------------------------------------------------------------

#define AS1 __attribute__((address_space(1)))
#define AS3 __attribute__((address_space(3)))
#define VMCNT(n) asm volatile("s_waitcnt vmcnt(" #n ")" ::: "memory")
#define LGKM(n)  asm volatile("s_waitcnt lgkmcnt(" #n ")" ::: "memory")
#define SBARRIER asm volatile("s_barrier" ::: "memory")
#define SB0 __builtin_amdgcn_sched_barrier(0)

typedef __bf16 bf16;
typedef __bf16 bf16x4 __attribute__((ext_vector_type(4)));
typedef __bf16 bf16x8 __attribute__((ext_vector_type(8)));
typedef float  f32x4  __attribute__((ext_vector_type(4)));
typedef float  f32x16 __attribute__((ext_vector_type(16)));

constexpr int BATCH = 16;
constexpr int S = 1024;
constexpr int D = 1024;
constexpr long NBSD = (long)BATCH * S * D;   // 16777216

constexpr int GBM = 256, GBN = 256, GBK = 32;
constexpr int NTK = 1024 / GBK;              // 32 K-tiles
constexpr int ARR = GBM * GBK;               // 8192 elems = 16 KB per array

__device__ __forceinline__ void stage16(const bf16* src, const bf16* dst) {
  __builtin_amdgcn_global_load_lds((const AS1 void*)src, (AS3 void*)dst, 16, 0, 0);
}

// ---------------------------------------------------------------------------
__global__ __launch_bounds__(256) void split_convert(
    const float* __restrict__ in, bf16* __restrict__ hi, bf16* __restrict__ lo, int n4) {
  int i = blockIdx.x * blockDim.x + threadIdx.x;
  int stride = gridDim.x * blockDim.x;
  for (; i < n4; i += stride) {
    f32x4 x = ((const f32x4*)in)[i];
    bf16x4 h, l;
#pragma unroll
    for (int j = 0; j < 4; ++j) {
      float v = x[j];
      bf16 hh = (bf16)v;
      h[j] = hh;
      l[j] = (bf16)(v - (float)hh);
    }
    ((bf16x4*)hi)[i] = h;
    ((bf16x4*)lo)[i] = l;
  }
}

// ---------------------------------------------------------------------------
__global__ __launch_bounds__(256) void transpose_convert(
    const float* __restrict__ v, bf16* __restrict__ vT) {
  __shared__ float tile[32][33];
  const int b = blockIdx.z;
  const int t0 = blockIdx.y * 32, d0 = blockIdx.x * 32;
  const int tx = threadIdx.x & 31, ty = threadIdx.x >> 5;
  const float* src = v + (long)b * S * D;
#pragma unroll
  for (int i = 0; i < 4; ++i)
    tile[ty + i * 8][tx] = src[(long)(t0 + ty + i * 8) * D + d0 + tx];
  __syncthreads();
  bf16* dst = vT + (long)b * D * S;
#pragma unroll
  for (int i = 0; i < 4; ++i)
    dst[(long)(d0 + ty + i * 8) * S + t0 + tx] = (bf16)tile[tx][ty + i * 8];
}

// ---------------------------------------------------------------------------
// Split-bf16 GEMM on mfma_f32_32x32x16_bf16. BM=BN=256, BK=32, 512 thr
// (8 waves 2x4, 128x64 out/wave = 4x2 frags of 32x32). LDS: 2 bufs x
// {Ah,Al,Bh,Bl} x 16KB = 128 KB. 3 phases/K-tile (hh, hl, lh), 16 MFMA each.
// vmcnt ledger (steady): P1 issues AhBh' -> queue 8, wait 6 (retires Bl(t));
// P2 issues Bl' -> wait 6 (retires Al(t)); P3 issues Al' -> wait 4 (retires
// Ah',Bh'). Never drains to 0 mid-loop.
template <int EPI>
__global__ __launch_bounds__(512, 2) void gemm32_split(
    const bf16* __restrict__ Ah_g, const bf16* __restrict__ Al_g, long a_bs,
    const bf16* __restrict__ Bh_g, const bf16* __restrict__ Bl_g, long b_bs,
    const float* __restrict__ bias,
    bf16* __restrict__ Ch, bf16* __restrict__ Cl,
    float* __restrict__ Cf, long c_bs) {
  __shared__ bf16 lds[2 * 4 * ARR];   // 128 KB

  const int tid = threadIdx.x;
  const int lane = tid & 63, wid = tid >> 6;
  const int wr = wid >> 2, wc = wid & 3;          // 2x4 wave grid
  const int lr = lane & 31;                       // row/col within 32-frag
  const int lk = lane >> 5;                       // k-half (0,1)

  // T1 bijective XCD swizzle (nwg=256)
  const int w = blockIdx.x;
  const int swz = (w & 7) * 32 + (w >> 3);
  int z, by, bx;
  if constexpr (EPI == 0) { z = 0; by = swz >> 2; bx = swz & 3; }
  else { z = swz >> 4; by = (swz >> 2) & 3; bx = swz & 3; }
  const long brow = (long)by * GBM, bcol = (long)bx * GBN;

  const bf16* A_h = Ah_g + (long)z * a_bs;
  const bf16* A_l = Al_g + (long)z * a_bs;
  const bf16* B_h = Bh_g + (long)z * b_bs;
  const bf16* B_l = Bl_g + (long)z * b_bs;

  const int srow = tid >> 2;                                  // 0..127
  const int csw = ((tid & 3) ^ ((srow >> 1) & 3)) * 8;        // source pre-swizzle
  const long asrc = (brow + srow) * 1024 + csw;
  const long bsrc = (bcol + srow) * 1024 + csw;
  const int dstoff = wid * 512;                               // wave-uniform base

  // fragment read offsets: row r in tile, k-slice s (K=16 each):
  //   chunk = 2*s + lk ; elem = r*32 + (chunk ^ ((r>>1)&3))*8
  int aoff[4][2], boff[2][2];
#pragma unroll
  for (int i = 0; i < 4; ++i) {
    const int r = wr * 128 + i * 32 + lr;
#pragma unroll
    for (int s = 0; s < 2; ++s)
      aoff[i][s] = r * 32 + (((2 * s + lk) ^ ((r >> 1) & 3)) * 8);
  }
#pragma unroll
  for (int j = 0; j < 2; ++j) {
    const int r = wc * 64 + j * 32 + lr;
#pragma unroll
    for (int s = 0; s < 2; ++s)
      boff[j][s] = r * 32 + (((2 * s + lk) ^ ((r >> 1) & 3)) * 8);
  }

  f32x16 acc[4][2] = {};
  bf16x8 ah[4][2], al[4][2], bh[2][2], bl[2][2];

#define STG(slot, arr, base, koff, rr) \
  stage16((base) + (koff) + (long)(rr) * 131072, \
          lds + ((slot) * 4 + (arr)) * ARR + (rr) * 4096 + dstoff)

#define CLUSTER(AF, BF) \
  __builtin_amdgcn_s_setprio(1); \
  _Pragma("unroll") \
  for (int s = 0; s < 2; ++s) \
    _Pragma("unroll") \
    for (int i = 0; i < 4; ++i) \
      _Pragma("unroll") \
      for (int j = 0; j < 2; ++j) \
        acc[i][j] = __builtin_amdgcn_mfma_f32_32x32x16_bf16(AF[i][s], BF[j][s], acc[i][j], 0, 0, 0); \
  __builtin_amdgcn_s_setprio(0)

  // ---- prologue: stage tile 0 (order Ah,Bh,Bl,Al); publish Ah,Bh
  STG(0, 0, A_h + asrc, 0, 0); STG(0, 0, A_h + asrc, 0, 1);
  STG(0, 2, B_h + bsrc, 0, 0); STG(0, 2, B_h + bsrc, 0, 1);
  STG(0, 3, B_l + bsrc, 0, 0); STG(0, 3, B_l + bsrc, 0, 1);
  STG(0, 1, A_l + asrc, 0, 0); STG(0, 1, A_l + asrc, 0, 1);
  VMCNT(4);          // Ah0,Bh0 retired; Bl0,Al0 in flight
  SBARRIER;

  for (int t = 0; t < NTK; ++t) {
    const int cur = t & 1, nxt = cur ^ 1;
    const long kn = (long)(t + 1) * GBK;
    const bool pf = (t + 1 < NTK);
    const bf16* lA_h = lds + (cur * 4 + 0) * ARR;
    const bf16* lA_l = lds + (cur * 4 + 1) * ARR;
    const bf16* lB_h = lds + (cur * 4 + 2) * ARR;
    const bf16* lB_l = lds + (cur * 4 + 3) * ARR;

    // ---- P1: read ah,bh | stage Ah',Bh' | vmcnt(6) | bar | lgkm0 | hh
#pragma unroll
    for (int i = 0; i < 4; ++i)
#pragma unroll
      for (int s = 0; s < 2; ++s) ah[i][s] = *(const bf16x8*)&lA_h[aoff[i][s]];
#pragma unroll
    for (int j = 0; j < 2; ++j)
#pragma unroll
      for (int s = 0; s < 2; ++s) bh[j][s] = *(const bf16x8*)&lB_h[boff[j][s]];
    if (pf) {
      STG(nxt, 0, A_h + asrc, kn, 0); STG(nxt, 0, A_h + asrc, kn, 1);
      STG(nxt, 2, B_h + bsrc, kn, 0); STG(nxt, 2, B_h + bsrc, kn, 1);
      VMCNT(6);      // retires Bl(t)
    } else {
      VMCNT(2);      // tail: retires Bl(t), Al(t) still in flight
    }
    SBARRIER; LGKM(0); SB0;
    CLUSTER(ah, bh);
    SBARRIER;

    // ---- P2: read bl | stage Bl' | vmcnt(6) | bar | lgkm0 | hl
#pragma unroll
    for (int j = 0; j < 2; ++j)
#pragma unroll
      for (int s = 0; s < 2; ++s) bl[j][s] = *(const bf16x8*)&lB_l[boff[j][s]];
    if (pf) {
      STG(nxt, 3, B_l + bsrc, kn, 0); STG(nxt, 3, B_l + bsrc, kn, 1);
      VMCNT(6);      // retires Al(t)
    } else {
      VMCNT(0);      // tail: retires Al(t)
    }
    SBARRIER; LGKM(0); SB0;
    CLUSTER(ah, bl);
    SBARRIER;

    // ---- P3: read al | stage Al' | vmcnt(4) | bar | lgkm0 | lh
#pragma unroll
    for (int i = 0; i < 4; ++i)
#pragma unroll
      for (int s = 0; s < 2; ++s) al[i][s] = *(const bf16x8*)&lA_l[aoff[i][s]];
    if (pf) {
      STG(nxt, 1, A_l + asrc, kn, 0); STG(nxt, 1, A_l + asrc, kn, 1);
      VMCNT(4);      // retires Ah',Bh' (visible for P1(t+1))
    }
    SBARRIER; LGKM(0); SB0;
    CLUSTER(al, bh);
    SBARRIER;
  }
#undef STG
#undef CLUSTER

  // Epilogue. 32x32 C/D frag [m74/m101]: col = lane&31,
  // row = (reg&3) + 8*(reg>>2) + 4*(lane>>5)
  if constexpr (EPI == 0) {
#pragma unroll
    for (int j = 0; j < 2; ++j) {
      const long col = bcol + wc * 64 + j * 32 + lr;
      const float bv = bias[col];
#pragma unroll
      for (int i = 0; i < 4; ++i) {
        const long row0 = brow + wr * 128 + i * 32 + 4 * lk;
#pragma unroll
        for (int r = 0; r < 16; ++r) {
          const long row = row0 + (r & 3) + 8 * (r >> 2);
          const float c = acc[i][j][r] + bv;
          const bf16 h = (bf16)c;
          const bf16 l = (bf16)(c - (float)h);
          const long idx = row * 1024 + col;
          Ch[idx] = h;
          Cl[idx] = l;
        }
      }
    }
  } else {
    float* Cz = Cf + (long)z * c_bs;
#pragma unroll
    for (int j = 0; j < 2; ++j) {
      const long col = bcol + wc * 64 + j * 32 + lr;
#pragma unroll
      for (int i = 0; i < 4; ++i) {
        const long row0 = brow + wr * 128 + i * 32 + 4 * lk;
#pragma unroll
        for (int r = 0; r < 16; ++r) {
          const long row = row0 + (r & 3) + 8 * (r >> 2);
          Cz[row * 1024 + col] = acc[i][j][r] + bias[row * 1024 + col];
        }
      }
    }
  }
}

// ---------------------------------------------------------------------------
// Plain bf16 GEMM (PV), R3 structure: 2 bufs x {A,B} = 64KB; per K-tile
// stage t+1 ; vmcnt(4) ; barrier ; 12 reads + 32 MFMA ; barrier.
__global__ __launch_bounds__(512, 2) void gemm8_plain(
    const bf16* __restrict__ A_g, long a_bs,
    const bf16* __restrict__ B_g, long b_bs,
    float* __restrict__ C, long c_bs) {
  __shared__ bf16 lds[2 * 2 * ARR];   // 64 KB

  const int tid = threadIdx.x;
  const int lane = tid & 63, wid = tid >> 6;
  const int wr = wid >> 2, wc = wid & 3;
  const int fr = lane & 15, fq = lane >> 4;
  const int fsw = (fr >> 1) & 3;

  const int w = blockIdx.x;
  const int swz = (w & 7) * 32 + (w >> 3);
  const int z = swz >> 4, by = (swz >> 2) & 3, bx = swz & 3;
  const long brow = (long)by * GBM, bcol = (long)bx * GBN;

  const bf16* A = A_g + (long)z * a_bs;
  const bf16* B = B_g + (long)z * b_bs;

  const int srow = tid >> 2;
  const int csw = ((tid & 3) ^ ((srow >> 1) & 3)) * 8;
  const long asrc = (brow + srow) * 1024 + csw;
  const long bsrc = (bcol + srow) * 1024 + csw;
  const int dstoff = wid * 512;

  const int aoffb = (wr * 128 + fr) * 32 + (fq ^ fsw) * 8;
  const int boffb = (wc * 64 + fr) * 32 + (fq ^ fsw) * 8;

  f32x4 acc[8][4] = {};

#define STG2(slot, arr, base, koff, rr) \
  stage16((base) + (koff) + (long)(rr) * 131072, \
          lds + ((slot) * 2 + (arr)) * ARR + (rr) * 4096 + dstoff)

  STG2(0, 0, A + asrc, 0, 0); STG2(0, 0, A + asrc, 0, 1);
  STG2(0, 1, B + bsrc, 0, 0); STG2(0, 1, B + bsrc, 0, 1);

  for (int t = 0; t < NTK; ++t) {
    const int cur = t & 1, nxt = cur ^ 1;
    const bf16* lA = lds + (cur * 2 + 0) * ARR;
    const bf16* lB = lds + (cur * 2 + 1) * ARR;

    if (t + 1 < NTK) {
      const long kn = (long)(t + 1) * GBK;
      STG2(nxt, 0, A + asrc, kn, 0); STG2(nxt, 0, A + asrc, kn, 1);
      STG2(nxt, 1, B + bsrc, kn, 0); STG2(nxt, 1, B + bsrc, kn, 1);
      VMCNT(4);
    } else {
      VMCNT(0);
    }
    SB0;
    SBARRIER;

    bf16x8 ah[8], bh[4];
#pragma unroll
    for (int m = 0; m < 8; ++m) ah[m] = *(const bf16x8*)&lA[aoffb + m * 512];
#pragma unroll
    for (int n = 0; n < 4; ++n) bh[n] = *(const bf16x8*)&lB[boffb + n * 512];
#pragma unroll
    for (int n = 0; n < 4; ++n)
#pragma unroll
      for (int m = 0; m < 8; ++m)
        acc[m][n] = __builtin_amdgcn_mfma_f32_16x16x32_bf16(ah[m], bh[n], acc[m][n], 0, 0, 0);

    SBARRIER;
  }
#undef STG2

  float* Cz = C + (long)z * c_bs;
#pragma unroll
  for (int n = 0; n < 4; ++n) {
    const long col = bcol + wc * 64 + n * 16 + fr;
#pragma unroll
    for (int m = 0; m < 8; ++m) {
      const long row0 = brow + wr * 128 + m * 16 + fq * 4;
#pragma unroll
      for (int j = 0; j < 4; ++j)
        Cz[(row0 + j) * 1024 + col] = acc[m][n][j];
    }
  }
}

// ---------------------------------------------------------------------------
__global__ __launch_bounds__(256) void softmax_rows(
    float* __restrict__ attn, bf16* __restrict__ attn_bf) {
  const long row = blockIdx.x;
  float* p = attn + row * 1024;
  const int tid = threadIdx.x, lane = tid & 63, wid = tid >> 6;

  f32x4 x = ((const f32x4*)p)[tid];
  float m = fmaxf(fmaxf(x[0], x[1]), fmaxf(x[2], x[3]));
#pragma unroll
  for (int off = 32; off; off >>= 1) m = fmaxf(m, __shfl_xor(m, off));
  __shared__ float redm[4];
  if (lane == 0) redm[wid] = m;
  __syncthreads();
  m = fmaxf(fmaxf(redm[0], redm[1]), fmaxf(redm[2], redm[3]));

  f32x4 e;
#pragma unroll
  for (int j = 0; j < 4; ++j) e[j] = __expf(x[j] - m);
  float s = e[0] + e[1] + e[2] + e[3];
#pragma unroll
  for (int off = 32; off; off >>= 1) s += __shfl_xor(s, off);
  __shared__ float reds[4];
  if (lane == 0) reds[wid] = s;
  __syncthreads();
  s = reds[0] + reds[1] + reds[2] + reds[3];

  const float inv = 1.0f / s;
  f32x4 r;
  bf16x4 rb;
#pragma unroll
  for (int j = 0; j < 4; ++j) {
    r[j] = e[j] * inv;
    rb[j] = (bf16)r[j];
  }
  ((f32x4*)p)[tid] = r;
  ((bf16x4*)(attn_bf + row * 1024))[tid] = rb;
}

// ---------------------------------------------------------------------------
extern "C" void kernel_launch(void* const* d_in, const int* in_sizes, int n_in,
                              void* d_out, int out_size, void* d_ws, size_t ws_size,
                              hipStream_t stream) {
  const float* query     = (const float*)d_in[0];
  const float* key       = (const float*)d_in[1];
  const float* value     = (const float*)d_in[2];
  const float* attn_bias = (const float*)d_in[3];
  const float* Wq        = (const float*)d_in[4];
  const float* bq        = (const float*)d_in[5];
  const float* Wk        = (const float*)d_in[6];
  const float* bk        = (const float*)d_in[7];

  float* out  = (float*)d_out;          // [16,1024,1024]
  float* attn = out + NBSD;             // [16,1024,1024]

  // ws carve (bf16 elements). Total = 6*NBSD + 4*D*D = 200 MiB.
  bf16* ws    = (bf16*)d_ws;
  bf16* q_hi  = ws;
  bf16* q_lo  = ws + NBSD;
  bf16* k_hi  = ws + 2 * NBSD;
  bf16* k_lo  = ws + 3 * NBSD;
  bf16* Wq_hi = ws + 4 * NBSD;
  bf16* Wq_lo = Wq_hi + (long)D * D;
  bf16* Wk_hi = Wq_lo + (long)D * D;
  bf16* Wk_lo = Wk_hi + (long)D * D;
  bf16* scr   = Wk_lo + (long)D * D;    // 2*NBSD scratch
  bf16* key_hi = scr;
  bf16* key_lo = scr + NBSD;
  bf16* valueT  = scr;                  // reused after key splits die
  bf16* attn_bf = scr + NBSD;
  bf16* query_hi = (bf16*)d_out;        // lives in `out` region until PV
  bf16* query_lo = query_hi + NBSD;

  // 1) split conversions
  split_convert<<<2048, 256, 0, stream>>>(query, query_hi, query_lo, (int)(NBSD / 4));
  split_convert<<<2048, 256, 0, stream>>>(key, key_hi, key_lo, (int)(NBSD / 4));
  split_convert<<<512, 256, 0, stream>>>(Wq, Wq_hi, Wq_lo, D * D / 4);
  split_convert<<<512, 256, 0, stream>>>(Wk, Wk_hi, Wk_lo, D * D / 4);

  // 2) projections: [16384,1024] x [1024,1024]^T (grid 64x4 = 256 blocks)
  gemm32_split<0><<<256, 512, 0, stream>>>(query_hi, query_lo, 0, Wq_hi, Wq_lo, 0,
                                           bq, q_hi, q_lo, nullptr, 0);
  gemm32_split<0><<<256, 512, 0, stream>>>(key_hi, key_lo, 0, Wk_hi, Wk_lo, 0,
                                           bk, k_hi, k_lo, nullptr, 0);

  // 3) value transpose (key splits now dead)
  transpose_convert<<<dim3(32, 32, 16), 256, 0, stream>>>(value, valueT);

  // 4) energy = q k^T + bias (grid 16 z x 4x4 = 256 blocks)
  gemm32_split<1><<<256, 512, 0, stream>>>(q_hi, q_lo, (long)S * D, k_hi, k_lo, (long)S * D,
                                           attn_bias, nullptr, nullptr, attn, (long)S * S);

  // 5) softmax in place + bf16 copy
  softmax_rows<<<BATCH * S, 256, 0, stream>>>(attn, attn_bf);

  // 6) out = attention @ value
  gemm8_plain<<<256, 512, 0, stream>>>(attn_bf, (long)S * S, valueT, (long)D * S,
                                       out, (long)S * D);
}